// Round 7
// baseline (71962.445 us; speedup 1.0000x reference)
//
#include <hip/hip_runtime.h>
#include <hip/hip_fp16.h>

#define NB 64
#define NT 1000
#define NH 512
#define NI 32
#define NO 32
#define ALPHA 0.05f
#define NOISE_STD 0.05f

#define LDW 72            // dwords per LDS column (144 rows as f16 pairs)
#define REGU 46           // uint4 register weight units (368 rows)

typedef unsigned int uint32;
typedef __attribute__((ext_vector_type(2))) _Float16 half2v;

static __device__ __forceinline__ float dot2f(uint32 a, uint32 b, float c) {
#if __has_builtin(__builtin_amdgcn_fdot2)
    return __builtin_amdgcn_fdot2(__builtin_bit_cast(half2v, a),
                                  __builtin_bit_cast(half2v, b), c, false);
#else
    half2v av = __builtin_bit_cast(half2v, a);
    half2v bv = __builtin_bit_cast(half2v, b);
    return c + (float)av[0] * (float)bv[0] + (float)av[1] * (float)bv[1];
#endif
}

static __device__ __forceinline__ uint32 pack2(float a, float b) {
    __half2 hp = __floats2half2_rn(a, b);
    return *(uint32*)&hp;
}

// swizzled dword offset for column j, dword u (u in [0,LDW))
static __device__ __forceinline__ int wl_off(int j, int u) {
    const int U = u >> 2;
    const int P = (U < 16) ? (U ^ (j & 15)) : U;
    return j * LDW + 4 * P + (u & 3);
}

// --------- precompute c[b][t][j] = NOISE_STD*noise + (ALPHA/tM_j)*(x_t @ wi)_j  (f16) ---------
__global__ __launch_bounds__(512) void precompute_c_kernel(
    const float* __restrict__ x, const float* __restrict__ noise,
    const float* __restrict__ wi, const float* __restrict__ tM,
    __half* __restrict__ cbuf)
{
    const int bt = blockIdx.x;      // b*NT + t
    const int j = threadIdx.x;
    __shared__ float xs[NI];
    if (j < NI) xs[j] = x[(size_t)bt * NI + j];
    __syncthreads();
    const float a_inv = ALPHA * (1.0f / tM[j]);
    const float nv = noise[(size_t)bt * NH + j];
    float xw = 0.f;
    #pragma unroll
    for (int i = 0; i < NI; ++i) xw += xs[i] * wi[i * NH + j];
    cbuf[(size_t)bt * NH + j] = __float2half(NOISE_STD * nv + a_inv * xw);
}

// One WG per batch. Thread j owns column j end-to-end.
// W' = (alpha/tM_j * g_j) * wrec: rows [0,144) in LDS (swizzled), rows [144,512) in VGPRs.
// amdgpu_waves_per_eu(2,2): 8 waves/CU -> 256-VGPR budget (the R5/R6 spill fix).
__global__
__attribute__((amdgpu_flat_work_group_size(512, 512), amdgpu_waves_per_eu(2, 2)))
void rnn_single_kernel(
    const float* __restrict__ wrec, const float* __restrict__ wout,
    const float* __restrict__ bias, const float* __restrict__ g,
    const float* __restrict__ tM, const float* __restrict__ h0,
    const __half* __restrict__ cbuf, float* __restrict__ out)
{
    __shared__ __align__(16) uint32 wl[NH * LDW];    // 147 KB: W' rows [0,144)
    __shared__ __align__(16) uint32 r32[NH / 2];     // 1 KB: r(t) f16 pairs

    const int b = blockIdx.x;
    const int j = threadIdx.x;
    const int w = j >> 6, l = j & 63;

    const float a_inv = ALPHA / tM[j];
    const float scale = a_inv * g[j];
    const float hs1 = 1.0f - a_inv;
    const float hb = a_inv * bias[j];
    float h = h0[j];

    // ---- stage W' rows [0,144) into LDS, swizzled f16 pairs ----
    // sched_barrier every 2 units bounds in-flight loads (prologue reg pressure)
    #pragma unroll
    for (int u = 0; u < LDW; ++u) {
        wl[wl_off(j, u)] = pack2(scale * wrec[(size_t)(2 * u) * NH + j],
                                 scale * wrec[(size_t)(2 * u + 1) * NH + j]);
        if ((u & 3) == 3) __builtin_amdgcn_sched_barrier(0);
    }

    // ---- W' rows [144,512) into registers: 46 uint4 = 184 dwords ----
    uint4 wr[REGU];
    #pragma unroll
    for (int u = 0; u < REGU; ++u) {
        const int base = 2 * LDW + 8 * u;
        wr[u].x = pack2(scale * wrec[(size_t)(base + 0) * NH + j],
                        scale * wrec[(size_t)(base + 1) * NH + j]);
        wr[u].y = pack2(scale * wrec[(size_t)(base + 2) * NH + j],
                        scale * wrec[(size_t)(base + 3) * NH + j]);
        wr[u].z = pack2(scale * wrec[(size_t)(base + 4) * NH + j],
                        scale * wrec[(size_t)(base + 5) * NH + j]);
        wr[u].w = pack2(scale * wrec[(size_t)(base + 6) * NH + j],
                        scale * wrec[(size_t)(base + 7) * NH + j]);
        if ((u & 1) == 1) __builtin_amdgcn_sched_barrier(0);
    }

    // ---- wout in registers: wave w -> cols 4w..4w+3, lane l -> rows 8l..8l+8 ----
    uint32 wor[4][4];
    #pragma unroll
    for (int c = 0; c < 4; ++c)
        #pragma unroll
        for (int u = 0; u < 4; ++u)
            wor[c][u] = pack2(wout[(size_t)(8 * l + 2 * u) * NO + 4 * w + c],
                              wout[(size_t)(8 * l + 2 * u + 1) * NO + 4 * w + c]);

    __syncthreads();

    const __half* cp = cbuf + (size_t)b * NT * NH + j;
    float* outp      = out + (size_t)b * NT * NO;

    for (int t = 0; t < NT; ++t) {
        // r(t) = relu(h) -> LDS f16
        ((unsigned short*)r32)[j] = __half_as_ushort(__float2half(fmaxf(h, 0.f)));
        __syncthreads();

        // per-step additive term (f16 cbuf; latency hides under matvec)
        const float cval = __half2float(cp[(size_t)t * NH]);

        // matvec rows [0,144) from LDS (swizzled b128)
        float a0 = 0.f, a1 = 0.f, a2 = 0.f, a3 = 0.f;
        #pragma unroll
        for (int U = 0; U < 18; ++U) {
            const uint4 rr = *(const uint4*)(r32 + 4 * U);              // broadcast
            const int P = (U < 16) ? (U ^ (j & 15)) : U;
            const uint4 ww = *(const uint4*)(wl + j * LDW + 4 * P);
            a0 = dot2f(ww.x, rr.x, a0); a1 = dot2f(ww.y, rr.y, a1);
            a2 = dot2f(ww.z, rr.z, a2); a3 = dot2f(ww.w, rr.w, a3);
        }
        // rows [144,512) from registers
        #pragma unroll
        for (int u = 0; u < REGU; ++u) {
            const uint4 rr = *(const uint4*)(r32 + 2 * LDW / 2 + 4 * u); // broadcast
            a0 = dot2f(wr[u].x, rr.x, a0); a1 = dot2f(wr[u].y, rr.y, a1);
            a2 = dot2f(wr[u].z, rr.z, a2); a3 = dot2f(wr[u].w, rr.w, a3);
        }
        const float acc = (a0 + a1) + (a2 + a3);

        // out-projection for row t: wave w covers cols 4w..4w+3
        {
            const uint4 rr = *(const uint4*)(r32 + 4 * l);              // coalesced
            #pragma unroll
            for (int c = 0; c < 4; ++c) {
                float oa = dot2f(wor[c][0], rr.x, 0.f);
                oa = dot2f(wor[c][1], rr.y, oa);
                oa = dot2f(wor[c][2], rr.z, oa);
                oa = dot2f(wor[c][3], rr.w, oa);
                oa += __shfl_xor(oa, 1, 64);
                oa += __shfl_xor(oa, 2, 64);
                oa += __shfl_xor(oa, 4, 64);
                oa += __shfl_xor(oa, 8, 64);
                oa += __shfl_xor(oa, 16, 64);
                oa += __shfl_xor(oa, 32, 64);
                if (l == 0) outp[(size_t)t * NO + 4 * w + c] = oa;
            }
        }

        // h <- h*(1-a) + a*b + [std*noise + a*(x@wi)] + a*g*(r@wrec)
        h = h * hs1 + hb + cval + acc;
        __syncthreads();   // protect r32 before next overwrite
    }
}

// --------- fallback (only if ws too small for cbuf) ---------
__global__ __launch_bounds__(1024, 1) void rnn_seq_kernel(
    const float* __restrict__ x, const float* __restrict__ noise,
    const float* __restrict__ wi, const float* __restrict__ wrec,
    const float* __restrict__ wout, const float* __restrict__ bias,
    const float* __restrict__ g, const float* __restrict__ tM,
    const float* __restrict__ h0, float* __restrict__ out)
{
    const int bidx = blockIdx.x;
    const int tid  = threadIdx.x;
    const int j    = tid & (NH - 1);
    const int half = tid >> 9;

    __shared__ float hs[NH];
    __shared__ float rs[NH];
    __shared__ float accb[NH];
    __shared__ float xt[NI];
    __shared__ float red[32][NO + 1];

    float a_inv = 0.f, gj = 0.f, bj = 0.f;
    if (tid < NH) {
        hs[tid] = h0[tid];
        a_inv   = ALPHA / tM[tid];
        gj      = g[tid];
        bj      = bias[tid];
    }
    __syncthreads();

    const int k   = tid & (NO - 1);
    const int seg = tid >> 5;

    for (int t = 0; t < NT; ++t) {
        if (tid < NH) rs[tid] = fmaxf(hs[tid], 0.f);
        if (t < NT - 1 && tid >= NH && tid < NH + NI)
            xt[tid - NH] = x[((size_t)bidx * NT + t) * NI + (tid - NH)];
        __syncthreads();

        float nv = 0.f;
        if (t < NT - 1 && tid < NH)
            nv = noise[((size_t)bidx * NT + t) * NH + tid];

        {
            float pp = 0.f;
            const int base = seg * 16;
            #pragma unroll
            for (int m = 0; m < 16; ++m)
                pp += rs[base + m] * wout[(base + m) * NO + k];
            red[seg][k] = pp;
        }

        float acc = 0.f;
        if (t < NT - 1) {
            const float* wrp = wrec + ((size_t)half * 256) * NH + j;
            const int rbase = half * 256;
            #pragma unroll 16
            for (int i = 0; i < 256; ++i)
                acc += rs[rbase + i] * wrp[(size_t)i * NH];
            if (half) accb[j] = acc;
        }
        __syncthreads();

        if (t < NT - 1 && tid < NH) {
            float accf = acc + accb[j];
            float xw = 0.f;
            #pragma unroll
            for (int i = 0; i < NI; ++i)
                xw += xt[i] * wi[i * NH + j];
            float hv = hs[j];
            hs[j] = hv + NOISE_STD * nv + a_inv * (-hv + gj * accf + bj + xw);
        }

        if (tid < NO) {
            float s = 0.f;
            #pragma unroll
            for (int sg = 0; sg < 32; ++sg) s += red[sg][tid];
            out[((size_t)bidx * NT + t) * NO + tid] = s;
        }
        __syncthreads();
    }
}

extern "C" void kernel_launch(void* const* d_in, const int* in_sizes, int n_in,
                              void* d_out, int out_size, void* d_ws, size_t ws_size,
                              hipStream_t stream) {
    const float* x     = (const float*)d_in[0];
    const float* noise = (const float*)d_in[1];
    const float* wi    = (const float*)d_in[2];
    const float* wrec  = (const float*)d_in[3];
    const float* wout  = (const float*)d_in[4];
    const float* bias  = (const float*)d_in[5];
    const float* g     = (const float*)d_in[6];
    const float* tM    = (const float*)d_in[7];
    const float* h0    = (const float*)d_in[8];
    float* out = (float*)d_out;

    const size_t cb_bytes = (size_t)NB * NT * NH * 2;   // 65,536,000

    if (ws_size >= cb_bytes) {
        __half* cbuf = (__half*)d_ws;
        precompute_c_kernel<<<NB * NT, 512, 0, stream>>>(x, noise, wi, tM, cbuf);
        rnn_single_kernel<<<NB, 512, 0, stream>>>(wrec, wout, bias, g, tM, h0, cbuf, out);
    } else {
        rnn_seq_kernel<<<NB, 1024, 0, stream>>>(x, noise, wi, wrec, wout, bias, g, tM, h0, out);
    }
}

// Round 8
// 66821.185 us; speedup vs baseline: 1.0769x; 1.0769x over previous
//
#include <hip/hip_runtime.h>
#include <hip/hip_fp16.h>

#define NB 64
#define NT 1000
#define NH 512
#define NI 32
#define NO 32
#define ALPHA 0.05f
#define NOISE_STD 0.05f

#define LDW 76            // dwords per LDS column -> 152 rows as f16 pairs (155.6 KB)
#define LDSROWS 152

typedef unsigned int uint32;
typedef __attribute__((ext_vector_type(2))) _Float16 half2v;

static __device__ __forceinline__ float dot2f(uint32 a, uint32 b, float c) {
#if __has_builtin(__builtin_amdgcn_fdot2)
    return __builtin_amdgcn_fdot2(__builtin_bit_cast(half2v, a),
                                  __builtin_bit_cast(half2v, b), c, false);
#else
    half2v av = __builtin_bit_cast(half2v, a);
    half2v bv = __builtin_bit_cast(half2v, b);
    return c + (float)av[0] * (float)bv[0] + (float)av[1] * (float)bv[1];
#endif
}

static __device__ __forceinline__ uint32 pack2(float a, float b) {
    __half2 hp = __floats2half2_rn(a, b);
    return *(uint32*)&hp;
}

// swizzled dword offset for column j, uint4-unit U (U in [0,19))
static __device__ __forceinline__ int wl_unit(int j, int U) {
    const int P = (U < 16) ? (U ^ (j & 15)) : U;
    return j * LDW + 4 * P;
}

// 45 register-weight units = 360 rows [152,512), as NAMED locals (no alloca!)
#define REP45(F) F(0) F(1) F(2) F(3) F(4) F(5) F(6) F(7) F(8) F(9) \
    F(10) F(11) F(12) F(13) F(14) F(15) F(16) F(17) F(18) F(19) \
    F(20) F(21) F(22) F(23) F(24) F(25) F(26) F(27) F(28) F(29) \
    F(30) F(31) F(32) F(33) F(34) F(35) F(36) F(37) F(38) F(39) \
    F(40) F(41) F(42) F(43) F(44)

// --------- precompute c[b][t][j] = NOISE_STD*noise + (ALPHA/tM_j)*(x_t @ wi)_j  (f16) ---------
__global__ __launch_bounds__(512) void precompute_c_kernel(
    const float* __restrict__ x, const float* __restrict__ noise,
    const float* __restrict__ wi, const float* __restrict__ tM,
    __half* __restrict__ cbuf)
{
    const int bt = blockIdx.x;      // b*NT + t
    const int j = threadIdx.x;
    __shared__ float xs[NI];
    if (j < NI) xs[j] = x[(size_t)bt * NI + j];
    __syncthreads();
    const float a_inv = ALPHA * (1.0f / tM[j]);
    const float nv = noise[(size_t)bt * NH + j];
    float xw = 0.f;
    #pragma unroll
    for (int i = 0; i < NI; ++i) xw += xs[i] * wi[i * NH + j];
    cbuf[(size_t)bt * NH + j] = __float2half(NOISE_STD * nv + a_inv * xw);
}

// One WG per batch. Thread j owns column j end-to-end.
// W' = (alpha/tM_j * g_j) * wrec: rows [0,152) in LDS (swizzled), rows [152,512)
// in 45 NAMED uint4 locals (180 VGPRs) — bypasses alloca/scratch entirely.
__global__
__attribute__((amdgpu_flat_work_group_size(512, 512), amdgpu_waves_per_eu(2, 2)))
void rnn_single_kernel(
    const float* __restrict__ wrec, const float* __restrict__ wout,
    const float* __restrict__ bias, const float* __restrict__ g,
    const float* __restrict__ tM, const float* __restrict__ h0,
    const __half* __restrict__ cbuf, float* __restrict__ out)
{
    __shared__ __align__(16) uint32 wl[NH * LDW];    // 155.6 KB: W' rows [0,152)
    __shared__ __align__(16) uint32 r32[NH / 2];     // 1 KB: r(t) f16 pairs

    const int b = blockIdx.x;
    const int j = threadIdx.x;
    const int w = j >> 6, l = j & 63;

    const float a_inv = ALPHA / tM[j];
    const float scale = a_inv * g[j];
    const float hs1 = 1.0f - a_inv;
    const float hb = a_inv * bias[j];
    float h = h0[j];

    // ---- stage W' rows [0,152) into LDS, swizzled f16 pairs ----
    #pragma unroll
    for (int U = 0; U < 19; ++U) {
        const int base = 8 * U;
        uint4 v;
        v.x = pack2(scale * wrec[(size_t)(base + 0) * NH + j],
                    scale * wrec[(size_t)(base + 1) * NH + j]);
        v.y = pack2(scale * wrec[(size_t)(base + 2) * NH + j],
                    scale * wrec[(size_t)(base + 3) * NH + j]);
        v.z = pack2(scale * wrec[(size_t)(base + 4) * NH + j],
                    scale * wrec[(size_t)(base + 5) * NH + j]);
        v.w = pack2(scale * wrec[(size_t)(base + 6) * NH + j],
                    scale * wrec[(size_t)(base + 7) * NH + j]);
        *(uint4*)(wl + wl_unit(j, U)) = v;
    }

    // ---- W' rows [152,512) into 45 named uint4 locals ----
#define DECLW(n) uint4 W##n;
    REP45(DECLW)
#undef DECLW

#define LOADW(n) { \
    const int base = LDSROWS + 8 * (n); \
    W##n.x = pack2(scale * wrec[(size_t)(base + 0) * NH + j], \
                   scale * wrec[(size_t)(base + 1) * NH + j]); \
    W##n.y = pack2(scale * wrec[(size_t)(base + 2) * NH + j], \
                   scale * wrec[(size_t)(base + 3) * NH + j]); \
    W##n.z = pack2(scale * wrec[(size_t)(base + 4) * NH + j], \
                   scale * wrec[(size_t)(base + 5) * NH + j]); \
    W##n.w = pack2(scale * wrec[(size_t)(base + 6) * NH + j], \
                   scale * wrec[(size_t)(base + 7) * NH + j]); }
    REP45(LOADW)
#undef LOADW

    // ---- wout in registers: wave w -> cols 4w..4w+3, lane l -> rows 8l..8l+8 ----
    uint32 wor00, wor01, wor02, wor03, wor10, wor11, wor12, wor13;
    uint32 wor20, wor21, wor22, wor23, wor30, wor31, wor32, wor33;
#define LW(cc, uu) pack2(wout[(size_t)(8 * l + 2 * (uu)) * NO + 4 * w + (cc)], \
                         wout[(size_t)(8 * l + 2 * (uu) + 1) * NO + 4 * w + (cc)])
    wor00 = LW(0,0); wor01 = LW(0,1); wor02 = LW(0,2); wor03 = LW(0,3);
    wor10 = LW(1,0); wor11 = LW(1,1); wor12 = LW(1,2); wor13 = LW(1,3);
    wor20 = LW(2,0); wor21 = LW(2,1); wor22 = LW(2,2); wor23 = LW(2,3);
    wor30 = LW(3,0); wor31 = LW(3,1); wor32 = LW(3,2); wor33 = LW(3,3);
#undef LW

    __syncthreads();

    const __half* cp = cbuf + (size_t)b * NT * NH + j;
    float* outp      = out + (size_t)b * NT * NO;

    for (int t = 0; t < NT; ++t) {
        // r(t) = relu(h) -> LDS f16
        ((unsigned short*)r32)[j] = __half_as_ushort(__float2half(fmaxf(h, 0.f)));
        __syncthreads();

        // per-step additive term (f16 cbuf; latency hides under matvec)
        const float cval = __half2float(cp[(size_t)t * NH]);

        float a0 = 0.f, a1 = 0.f, a2 = 0.f, a3 = 0.f;
        // matvec rows [0,152) from LDS (swizzled b128)
        #pragma unroll
        for (int U = 0; U < 19; ++U) {
            const uint4 rr = *(const uint4*)(r32 + 4 * U);              // broadcast
            const uint4 ww = *(const uint4*)(wl + wl_unit(j, U));
            a0 = dot2f(ww.x, rr.x, a0); a1 = dot2f(ww.y, rr.y, a1);
            a2 = dot2f(ww.z, rr.z, a2); a3 = dot2f(ww.w, rr.w, a3);
        }
        // rows [152,512) from named register weights
#define MACW(n) { \
    const uint4 rr = *(const uint4*)(r32 + LDW + 4 * (n)); \
    a0 = dot2f(W##n.x, rr.x, a0); a1 = dot2f(W##n.y, rr.y, a1); \
    a2 = dot2f(W##n.z, rr.z, a2); a3 = dot2f(W##n.w, rr.w, a3); }
        REP45(MACW)
#undef MACW
        const float acc = (a0 + a1) + (a2 + a3);

        // out-projection for row t: wave w covers cols 4w..4w+3
        {
            const uint4 rr = *(const uint4*)(r32 + 4 * l);              // coalesced
#define OPROJ(c, w0, w1, w2, w3) { \
    float oa = dot2f(w0, rr.x, 0.f); \
    oa = dot2f(w1, rr.y, oa); \
    oa = dot2f(w2, rr.z, oa); \
    oa = dot2f(w3, rr.w, oa); \
    oa += __shfl_xor(oa, 1, 64);  oa += __shfl_xor(oa, 2, 64); \
    oa += __shfl_xor(oa, 4, 64);  oa += __shfl_xor(oa, 8, 64); \
    oa += __shfl_xor(oa, 16, 64); oa += __shfl_xor(oa, 32, 64); \
    if (l == 0) outp[(size_t)t * NO + 4 * w + (c)] = oa; }
            OPROJ(0, wor00, wor01, wor02, wor03)
            OPROJ(1, wor10, wor11, wor12, wor13)
            OPROJ(2, wor20, wor21, wor22, wor23)
            OPROJ(3, wor30, wor31, wor32, wor33)
#undef OPROJ
        }

        // h <- h*(1-a) + a*b + [std*noise + a*(x@wi)] + a*g*(r@wrec)
        h = h * hs1 + hb + cval + acc;
        __syncthreads();   // protect r32 before next overwrite
    }
}

// --------- fallback (only if ws too small for cbuf) ---------
__global__ __launch_bounds__(1024, 1) void rnn_seq_kernel(
    const float* __restrict__ x, const float* __restrict__ noise,
    const float* __restrict__ wi, const float* __restrict__ wrec,
    const float* __restrict__ wout, const float* __restrict__ bias,
    const float* __restrict__ g, const float* __restrict__ tM,
    const float* __restrict__ h0, float* __restrict__ out)
{
    const int bidx = blockIdx.x;
    const int tid  = threadIdx.x;
    const int j    = tid & (NH - 1);
    const int half = tid >> 9;

    __shared__ float hs[NH];
    __shared__ float rs[NH];
    __shared__ float accb[NH];
    __shared__ float xt[NI];
    __shared__ float red[32][NO + 1];

    float a_inv = 0.f, gj = 0.f, bj = 0.f;
    if (tid < NH) {
        hs[tid] = h0[tid];
        a_inv   = ALPHA / tM[tid];
        gj      = g[tid];
        bj      = bias[tid];
    }
    __syncthreads();

    const int k   = tid & (NO - 1);
    const int seg = tid >> 5;

    for (int t = 0; t < NT; ++t) {
        if (tid < NH) rs[tid] = fmaxf(hs[tid], 0.f);
        if (t < NT - 1 && tid >= NH && tid < NH + NI)
            xt[tid - NH] = x[((size_t)bidx * NT + t) * NI + (tid - NH)];
        __syncthreads();

        float nv = 0.f;
        if (t < NT - 1 && tid < NH)
            nv = noise[((size_t)bidx * NT + t) * NH + tid];

        {
            float pp = 0.f;
            const int base = seg * 16;
            #pragma unroll
            for (int m = 0; m < 16; ++m)
                pp += rs[base + m] * wout[(base + m) * NO + k];
            red[seg][k] = pp;
        }

        float acc = 0.f;
        if (t < NT - 1) {
            const float* wrp = wrec + ((size_t)half * 256) * NH + j;
            const int rbase = half * 256;
            #pragma unroll 16
            for (int i = 0; i < 256; ++i)
                acc += rs[rbase + i] * wrp[(size_t)i * NH];
            if (half) accb[j] = acc;
        }
        __syncthreads();

        if (t < NT - 1 && tid < NH) {
            float accf = acc + accb[j];
            float xw = 0.f;
            #pragma unroll
            for (int i = 0; i < NI; ++i)
                xw += xt[i] * wi[i * NH + j];
            float hv = hs[j];
            hs[j] = hv + NOISE_STD * nv + a_inv * (-hv + gj * accf + bj + xw);
        }

        if (tid < NO) {
            float s = 0.f;
            #pragma unroll
            for (int sg = 0; sg < 32; ++sg) s += red[sg][tid];
            out[((size_t)bidx * NT + t) * NO + tid] = s;
        }
        __syncthreads();
    }
}

extern "C" void kernel_launch(void* const* d_in, const int* in_sizes, int n_in,
                              void* d_out, int out_size, void* d_ws, size_t ws_size,
                              hipStream_t stream) {
    const float* x     = (const float*)d_in[0];
    const float* noise = (const float*)d_in[1];
    const float* wi    = (const float*)d_in[2];
    const float* wrec  = (const float*)d_in[3];
    const float* wout  = (const float*)d_in[4];
    const float* bias  = (const float*)d_in[5];
    const float* g     = (const float*)d_in[6];
    const float* tM    = (const float*)d_in[7];
    const float* h0    = (const float*)d_in[8];
    float* out = (float*)d_out;

    const size_t cb_bytes = (size_t)NB * NT * NH * 2;   // 65,536,000

    if (ws_size >= cb_bytes) {
        __half* cbuf = (__half*)d_ws;
        precompute_c_kernel<<<NB * NT, 512, 0, stream>>>(x, noise, wi, tM, cbuf);
        rnn_single_kernel<<<NB, 512, 0, stream>>>(wrec, wout, bias, g, tM, h0, cbuf, out);
    } else {
        rnn_seq_kernel<<<NB, 1024, 0, stream>>>(x, noise, wi, wrec, wout, bias, g, tM, h0, out);
    }
}

// Round 10
// 39925.842 us; speedup vs baseline: 1.8024x; 1.6736x over previous
//
#include <hip/hip_runtime.h>
#include <hip/hip_fp16.h>

#define NB 64
#define NT 1000
#define NH 512
#define NI 32
#define NO 32
#define ALPHA 0.05f
#define NOISE_STD 0.05f

typedef unsigned int uint32;
typedef __attribute__((ext_vector_type(2))) _Float16 half2v;

static __device__ __forceinline__ float dot2f(uint32 a, uint32 b, float c) {
#if __has_builtin(__builtin_amdgcn_fdot2)
    return __builtin_amdgcn_fdot2(__builtin_bit_cast(half2v, a),
                                  __builtin_bit_cast(half2v, b), c, false);
#else
    half2v av = __builtin_bit_cast(half2v, a);
    half2v bv = __builtin_bit_cast(half2v, b);
    return c + (float)av[0] * (float)bv[0] + (float)av[1] * (float)bv[1];
#endif
}

static __device__ __forceinline__ uint32 pack2(float a, float b) {
    __half2 hp = __floats2half2_rn(a, b);
    return *(uint32*)&hp;
}

// 23 register-weight units (uint4 = 8 rows each) as NAMED locals
#define REP23(F) F(0) F(1) F(2) F(3) F(4) F(5) F(6) F(7) F(8) F(9) \
    F(10) F(11) F(12) F(13) F(14) F(15) F(16) F(17) F(18) F(19) \
    F(20) F(21) F(22)

// --------- precompute c[b][t][j] = NOISE_STD*noise + (ALPHA/tM_j)*(x_t @ wi)_j  (f16) ---------
__global__ __launch_bounds__(512) void precompute_c_kernel(
    const float* __restrict__ x, const float* __restrict__ noise,
    const float* __restrict__ wi, const float* __restrict__ tM,
    __half* __restrict__ cbuf)
{
    const int bt = blockIdx.x;      // b*NT + t
    const int j = threadIdx.x;
    __shared__ float xs[NI];
    if (j < NI) xs[j] = x[(size_t)bt * NI + j];
    __syncthreads();
    const float a_inv = ALPHA * (1.0f / tM[j]);
    const float nv = noise[(size_t)bt * NH + j];
    float xw = 0.f;
    #pragma unroll
    for (int i = 0; i < NI; ++i) xw += xs[i] * wi[i * NH + j];
    cbuf[(size_t)bt * NH + j] = __float2half(NOISE_STD * nv + a_inv * xw);
}

// One WG (1024 threads) per batch. Thread (j, half) owns rows [256*half, 256*half+256)
// of W' column j (W' = (alpha/tM_j*g_j)*wrec): 72 rows in LDS + 184 rows in 23 named
// uint4 locals (92 VGPRs). wout in 8 named regs/thread (wave w -> cols 2w,2w+1).
// Split-K partials exchanged through parity-double-buffered LDS.
__global__ __launch_bounds__(1024, 1) void rnn_splitk_kernel(
    const float* __restrict__ wrec, const float* __restrict__ wout,
    const float* __restrict__ bias, const float* __restrict__ g,
    const float* __restrict__ tM, const float* __restrict__ h0,
    const __half* __restrict__ cbuf, float* __restrict__ out)
{
    __shared__ __align__(16) uint32 wlds[2 * NH * 36];  // 144 KB: W' LDS rows
    __shared__ __align__(16) uint32 r32[NH / 2];        // 1 KB: r(t) f16 pairs
    __shared__ float red[2][NH];                        // 4 KB: split-K partials (parity)

    const int b    = blockIdx.x;
    const int tid  = threadIdx.x;
    const int j    = tid & (NH - 1);
    const int half = tid >> 9;
    const int w    = tid >> 6;      // wave 0..15
    const int l    = tid & 63;

    const float a_inv = ALPHA / tM[j];
    const float scale = a_inv * g[j];
    const float hs1 = 1.0f - a_inv;
    const float hb = a_inv * bias[j];
    float h = h0[j];                // only meaningful for half==0

    const int colbase = ((half << 9) + j) * 36;   // dword base of this (half, col) LDS block
    const int rowb = half * 256;                  // first owned row

    // ---- stage LDS weight rows [rowb, rowb+72): 9 units, XOR-swizzled ----
    #pragma unroll
    for (int U = 0; U < 9; ++U) {
        const int base = rowb + 8 * U;
        uint4 v;
        v.x = pack2(scale * wrec[(size_t)(base + 0) * NH + j],
                    scale * wrec[(size_t)(base + 1) * NH + j]);
        v.y = pack2(scale * wrec[(size_t)(base + 2) * NH + j],
                    scale * wrec[(size_t)(base + 3) * NH + j]);
        v.z = pack2(scale * wrec[(size_t)(base + 4) * NH + j],
                    scale * wrec[(size_t)(base + 5) * NH + j]);
        v.w = pack2(scale * wrec[(size_t)(base + 6) * NH + j],
                    scale * wrec[(size_t)(base + 7) * NH + j]);
        const int swz = (U < 8) ? (U ^ (j & 7)) : 8;
        *(uint4*)(wlds + colbase + 4 * swz) = v;
    }

    // ---- stage register weight rows [rowb+72, rowb+256): 23 named uint4 ----
#define DECLW(n) uint4 W##n;
    REP23(DECLW)
#undef DECLW
#define LOADW(n) { \
    const int base = rowb + 72 + 8 * (n); \
    W##n.x = pack2(scale * wrec[(size_t)(base + 0) * NH + j], \
                   scale * wrec[(size_t)(base + 1) * NH + j]); \
    W##n.y = pack2(scale * wrec[(size_t)(base + 2) * NH + j], \
                   scale * wrec[(size_t)(base + 3) * NH + j]); \
    W##n.z = pack2(scale * wrec[(size_t)(base + 4) * NH + j], \
                   scale * wrec[(size_t)(base + 5) * NH + j]); \
    W##n.w = pack2(scale * wrec[(size_t)(base + 6) * NH + j], \
                   scale * wrec[(size_t)(base + 7) * NH + j]); }
    REP23(LOADW)
#undef LOADW

    // ---- wout in 8 named regs: wave w -> cols 2w,2w+1; lane l -> rows [8l, 8l+8) ----
    uint32 wa0, wa1, wa2, wa3, wb0, wb1, wb2, wb3;
    {
        const int ca = 2 * w, cb = 2 * w + 1;
        wa0 = pack2(wout[(size_t)(8 * l + 0) * NO + ca], wout[(size_t)(8 * l + 1) * NO + ca]);
        wa1 = pack2(wout[(size_t)(8 * l + 2) * NO + ca], wout[(size_t)(8 * l + 3) * NO + ca]);
        wa2 = pack2(wout[(size_t)(8 * l + 4) * NO + ca], wout[(size_t)(8 * l + 5) * NO + ca]);
        wa3 = pack2(wout[(size_t)(8 * l + 6) * NO + ca], wout[(size_t)(8 * l + 7) * NO + ca]);
        wb0 = pack2(wout[(size_t)(8 * l + 0) * NO + cb], wout[(size_t)(8 * l + 1) * NO + cb]);
        wb1 = pack2(wout[(size_t)(8 * l + 2) * NO + cb], wout[(size_t)(8 * l + 3) * NO + cb]);
        wb2 = pack2(wout[(size_t)(8 * l + 4) * NO + cb], wout[(size_t)(8 * l + 5) * NO + cb]);
        wb3 = pack2(wout[(size_t)(8 * l + 6) * NO + cb], wout[(size_t)(8 * l + 7) * NO + cb]);
    }
    __syncthreads();

    const __half* cp = cbuf + (size_t)b * NT * NH + j;
    float* outp      = out + (size_t)b * NT * NO;
    const uint32* rb = r32 + (half << 7);     // this half's 128-dword r block

    for (int t = 0; t < NT; ++t) {
        // publish r(t) = relu(h) (owners = half 0)
        if (half == 0)
            ((unsigned short*)r32)[j] = __half_as_ushort(__float2half(fmaxf(h, 0.f)));
        __syncthreads();

        // per-step additive term (hides under matvec)
        float cval = 0.f;
        if (half == 0) cval = __half2float(cp[(size_t)t * NH]);

        // matvec partial: 9 LDS units + 23 register units (= 256 rows)
        float a0 = 0.f, a1 = 0.f, a2 = 0.f, a3 = 0.f;
        #pragma unroll
        for (int U = 0; U < 9; ++U) {
            const uint4 rr = *(const uint4*)(rb + 4 * U);               // broadcast
            const int swz = (U < 8) ? (U ^ (j & 7)) : 8;
            const uint4 ww = *(const uint4*)(wlds + colbase + 4 * swz);
            a0 = dot2f(ww.x, rr.x, a0); a1 = dot2f(ww.y, rr.y, a1);
            a2 = dot2f(ww.z, rr.z, a2); a3 = dot2f(ww.w, rr.w, a3);
        }
#define MACW(n) { \
    const uint4 rr = *(const uint4*)(rb + 36 + 4 * (n)); \
    a0 = dot2f(W##n.x, rr.x, a0); a1 = dot2f(W##n.y, rr.y, a1); \
    a2 = dot2f(W##n.z, rr.z, a2); a3 = dot2f(W##n.w, rr.w, a3); }
        REP23(MACW)
#undef MACW

        // out-projection for row t: wave w covers cols 2w, 2w+1 (reg wout)
        {
            const uint4 rr = *(const uint4*)(r32 + 4 * l);              // rows 8l..8l+8
            float oa = dot2f(wa0, rr.x, 0.f);
            oa = dot2f(wa1, rr.y, oa);
            oa = dot2f(wa2, rr.z, oa);
            oa = dot2f(wa3, rr.w, oa);
            float ob = dot2f(wb0, rr.x, 0.f);
            ob = dot2f(wb1, rr.y, ob);
            ob = dot2f(wb2, rr.z, ob);
            ob = dot2f(wb3, rr.w, ob);
            oa += __shfl_xor(oa, 1, 64);  ob += __shfl_xor(ob, 1, 64);
            oa += __shfl_xor(oa, 2, 64);  ob += __shfl_xor(ob, 2, 64);
            oa += __shfl_xor(oa, 4, 64);  ob += __shfl_xor(ob, 4, 64);
            oa += __shfl_xor(oa, 8, 64);  ob += __shfl_xor(ob, 8, 64);
            oa += __shfl_xor(oa, 16, 64); ob += __shfl_xor(ob, 16, 64);
            oa += __shfl_xor(oa, 32, 64); ob += __shfl_xor(ob, 32, 64);
            if (l == 0) {
                outp[(size_t)t * NO + 2 * w]     = oa;
                outp[(size_t)t * NO + 2 * w + 1] = ob;
            }
        }

        // exchange split-K partial (parity-buffered -> no extra barrier)
        if (half) red[t & 1][j] = (a0 + a1) + (a2 + a3);
        __syncthreads();

        // h update (owners)
        if (half == 0 && t < NT - 1)
            h = h * hs1 + hb + cval + ((a0 + a1) + (a2 + a3)) + red[t & 1][j];
    }
}

// --------- fallback (only if ws too small for cbuf) ---------
__global__ __launch_bounds__(1024, 1) void rnn_seq_kernel(
    const float* __restrict__ x, const float* __restrict__ noise,
    const float* __restrict__ wi, const float* __restrict__ wrec,
    const float* __restrict__ wout, const float* __restrict__ bias,
    const float* __restrict__ g, const float* __restrict__ tM,
    const float* __restrict__ h0, float* __restrict__ out)
{
    const int bidx = blockIdx.x;
    const int tid  = threadIdx.x;
    const int j    = tid & (NH - 1);
    const int half = tid >> 9;

    __shared__ float hs[NH];
    __shared__ float rs[NH];
    __shared__ float accb[NH];
    __shared__ float xt[NI];
    __shared__ float red[32][NO + 1];

    float a_inv = 0.f, gj = 0.f, bj = 0.f;
    if (tid < NH) {
        hs[tid] = h0[tid];
        a_inv   = ALPHA / tM[tid];
        gj      = g[tid];
        bj      = bias[tid];
    }
    __syncthreads();

    const int k   = tid & (NO - 1);
    const int seg = tid >> 5;

    for (int t = 0; t < NT; ++t) {
        if (tid < NH) rs[tid] = fmaxf(hs[tid], 0.f);
        if (t < NT - 1 && tid >= NH && tid < NH + NI)
            xt[tid - NH] = x[((size_t)bidx * NT + t) * NI + (tid - NH)];
        __syncthreads();

        float nv = 0.f;
        if (t < NT - 1 && tid < NH)
            nv = noise[((size_t)bidx * NT + t) * NH + tid];

        {
            float pp = 0.f;
            const int base = seg * 16;
            #pragma unroll
            for (int m = 0; m < 16; ++m)
                pp += rs[base + m] * wout[(base + m) * NO + k];
            red[seg][k] = pp;
        }

        float acc = 0.f;
        if (t < NT - 1) {
            const float* wrp = wrec + ((size_t)half * 256) * NH + j;
            const int rbase = half * 256;
            #pragma unroll 16
            for (int i = 0; i < 256; ++i)
                acc += rs[rbase + i] * wrp[(size_t)i * NH];
            if (half) accb[j] = acc;
        }
        __syncthreads();

        if (t < NT - 1 && tid < NH) {
            float accf = acc + accb[j];
            float xw = 0.f;
            #pragma unroll
            for (int i = 0; i < NI; ++i)
                xw += xt[i] * wi[i * NH + j];
            float hv = hs[j];
            hs[j] = hv + NOISE_STD * nv + a_inv * (-hv + gj * accf + bj + xw);
        }

        if (tid < NO) {
            float s = 0.f;
            #pragma unroll
            for (int sg = 0; sg < 32; ++sg) s += red[sg][tid];
            out[((size_t)bidx * NT + t) * NO + tid] = s;
        }
        __syncthreads();
    }
}

extern "C" void kernel_launch(void* const* d_in, const int* in_sizes, int n_in,
                              void* d_out, int out_size, void* d_ws, size_t ws_size,
                              hipStream_t stream) {
    const float* x     = (const float*)d_in[0];
    const float* noise = (const float*)d_in[1];
    const float* wi    = (const float*)d_in[2];
    const float* wrec  = (const float*)d_in[3];
    const float* wout  = (const float*)d_in[4];
    const float* bias  = (const float*)d_in[5];
    const float* g     = (const float*)d_in[6];
    const float* tM    = (const float*)d_in[7];
    const float* h0    = (const float*)d_in[8];
    float* out = (float*)d_out;

    const size_t cb_bytes = (size_t)NB * NT * NH * 2;   // 65,536,000

    if (ws_size >= cb_bytes) {
        __half* cbuf = (__half*)d_ws;
        precompute_c_kernel<<<NB * NT, 512, 0, stream>>>(x, noise, wi, tM, cbuf);
        rnn_splitk_kernel<<<NB, 1024, 0, stream>>>(wrec, wout, bias, g, tM, h0, cbuf, out);
    } else {
        rnn_seq_kernel<<<NB, 1024, 0, stream>>>(x, noise, wi, wrec, wout, bias, g, tM, h0, out);
    }
}